// Round 17
// baseline (2530.433 us; speedup 1.0000x reference)
//
#include <hip/hip_runtime.h>
#include <math.h>

// MoE-GPT forward, round 17: all GEMM staging switched from reg-staged LDS to
// __builtin_amdgcn_global_load_lds width=16 (m97 structure; +35% per m151).
// R1's gload_lds was exonerated by R2/R12 bisects (failures were routing
// precision). LDS layout already matches the wave-uniform+lane*16B contract.

#define NTOK  4096
#define CDIM  1024
#define HEADS 16
#define DHEAD 64
#define LAYERS 3
#define NEXP  8
#define DEXP  1024
#define TSEQ  512
#define FFDIM 4096
#define VOCAB 32000
#define C3    3072

typedef __attribute__((ext_vector_type(8))) short short8;
typedef __attribute__((ext_vector_type(4))) float f32x4;

#define GLDS(gp, lp) __builtin_amdgcn_global_load_lds( \
    (const __attribute__((address_space(1))) void*)(gp), \
    (__attribute__((address_space(3))) void*)(lp), 16, 0, 0)

__device__ __forceinline__ unsigned short f2bf(float f) {
  unsigned int u = __builtin_bit_cast(unsigned int, f);
  return (unsigned short)((u + 0x7fffu + ((u >> 16) & 1u)) >> 16);  // RNE
}
__device__ __forceinline__ float bf2f(unsigned short h) {
  return __builtin_bit_cast(float, ((unsigned int)h) << 16);
}

// ---------------- embedding gather ----------------
__global__ __launch_bounds__(256) void embed_kernel(const int* __restrict__ idx,
                                                    const float* __restrict__ emb,
                                                    float* __restrict__ x) {
  int i = blockIdx.x * 256 + threadIdx.x;
  int n = i >> 8, c4 = i & 255;
  const float4* src = (const float4*)(emb + (size_t)idx[n] * CDIM);
  ((float4*)(x + (size_t)n * CDIM))[c4] = src[c4];
}

// ---------------- RoPE cos/sin table [T][32] ----------------
__global__ void rope_table_kernel(float* __restrict__ ct, float* __restrict__ st) {
  int t = blockIdx.x, p = threadIdx.x;
  float inv = powf(10000.0f, -(float)p / 32.0f);
  float ang = (float)t * inv;
  ct[t * 32 + p] = cosf(ang);
  st[t * 32 + p] = sinf(ang);
}

// ---------------- qkv prep: RoPE + 3-way split + head-major relayout (R13 proven) ----------------
__global__ __launch_bounds__(256) void qkv_prep_kernel(
    const float* __restrict__ qkv, const float* __restrict__ ct,
    const float* __restrict__ st,
    unsigned short* __restrict__ Qh, unsigned short* __restrict__ Qm,
    unsigned short* __restrict__ Ql,
    unsigned short* __restrict__ Kh, unsigned short* __restrict__ Km,
    unsigned short* __restrict__ Kl,
    unsigned short* __restrict__ Vth, unsigned short* __restrict__ Vtm,
    unsigned short* __restrict__ Vtl) {
  __shared__ unsigned short sVh[64 * 64], sVm[64 * 64], sVl[64 * 64];  // [d][t]
  const int tid = threadIdx.x;
  const int tt0 = blockIdx.x * 64, h = blockIdx.y, b = blockIdx.z;
  const int bh = b * HEADS + h;
#pragma unroll
  for (int u = 0; u < 8; u++) {
    int pidx = tid + u * 256;
    int tl = pidx >> 5, p = pidx & 31;
    int t = tt0 + tl;
    size_t nb = ((size_t)(b * TSEQ + t)) * C3 + h * DHEAD;
    float c0 = ct[t * 32 + p], s0 = st[t * 32 + p];
    size_t ob = ((size_t)bh * TSEQ + t) * 64;
    float a = qkv[nb + p], bb = qkv[nb + p + 32];
    float lo = a * c0 - bb * s0, hi = bb * c0 + a * s0;
    unsigned short w0, w1;
    float r;
    w0 = f2bf(lo); r = lo - bf2f(w0); w1 = f2bf(r); r -= bf2f(w1);
    Qh[ob + p] = w0; Qm[ob + p] = w1; Ql[ob + p] = f2bf(r);
    w0 = f2bf(hi); r = hi - bf2f(w0); w1 = f2bf(r); r -= bf2f(w1);
    Qh[ob + p + 32] = w0; Qm[ob + p + 32] = w1; Ql[ob + p + 32] = f2bf(r);
    a = qkv[nb + CDIM + p]; bb = qkv[nb + CDIM + p + 32];
    lo = a * c0 - bb * s0; hi = bb * c0 + a * s0;
    w0 = f2bf(lo); r = lo - bf2f(w0); w1 = f2bf(r); r -= bf2f(w1);
    Kh[ob + p] = w0; Km[ob + p] = w1; Kl[ob + p] = f2bf(r);
    w0 = f2bf(hi); r = hi - bf2f(w0); w1 = f2bf(r); r -= bf2f(w1);
    Kh[ob + p + 32] = w0; Km[ob + p + 32] = w1; Kl[ob + p + 32] = f2bf(r);
  }
#pragma unroll
  for (int u = 0; u < 4; u++) {
    int vidx = tid + u * 256;
    int tl = vidx >> 4, d4 = (vidx & 15) * 4;
    int t = tt0 + tl;
    float4 v = *(const float4*)(qkv + ((size_t)(b * TSEQ + t)) * C3 + 2 * CDIM + h * DHEAD + d4);
    float vv[4] = {v.x, v.y, v.z, v.w};
#pragma unroll
    for (int j = 0; j < 4; j++) {
      unsigned short w0 = f2bf(vv[j]);
      float r = vv[j] - bf2f(w0);
      unsigned short w1 = f2bf(r);
      r -= bf2f(w1);
      sVh[(d4 + j) * 64 + tl] = w0;
      sVm[(d4 + j) * 64 + tl] = w1;
      sVl[(d4 + j) * 64 + tl] = f2bf(r);
    }
  }
  __syncthreads();
#pragma unroll
  for (int u = 0; u < 2; u++) {
    int idx = tid + u * 256;
    int d = idx >> 3, seg = (idx & 7) * 8;
    size_t go = ((size_t)bh * 64 + d) * TSEQ + tt0 + seg;
    *(short8*)(Vth + go) = *(const short8*)(sVh + d * 64 + seg);
    *(short8*)(Vtm + go) = *(const short8*)(sVm + d * 64 + seg);
    *(short8*)(Vtl + go) = *(const short8*)(sVl + d * 64 + seg);
  }
}

// ---------------- flash attention, 3-way split (R13/R14 proven), split output ----------------
__global__ __launch_bounds__(256) void flash_attn_kernel(
    const unsigned short* __restrict__ Qh, const unsigned short* __restrict__ Qm,
    const unsigned short* __restrict__ Ql,
    const unsigned short* __restrict__ Kh, const unsigned short* __restrict__ Km,
    const unsigned short* __restrict__ Kl,
    const unsigned short* __restrict__ Vth, const unsigned short* __restrict__ Vtm,
    const unsigned short* __restrict__ Vtl,
    unsigned short* __restrict__ ath, unsigned short* __restrict__ atl) {
  __shared__ __align__(16) unsigned short sK[3][2][64 * 32];
  __shared__ __align__(16) unsigned short sV[3][2][64 * 32];
  __shared__ __align__(16) unsigned short sP[3][2][4][16 * 32];
  const int tid = threadIdx.x;
  const int wv = tid >> 6, ln = tid & 63;
  const int qt = blockIdx.x, h = blockIdx.y, b = blockIdx.z;
  const int bh = b * HEADS + h;
  const int lr = ln & 15, lg = ln >> 4;
  const int q0 = qt * 64 + wv * 16;

  const size_t qoff = ((size_t)bh * TSEQ + q0 + lr) * 64 + 8 * lg;
  short8 qf[3][2];
  qf[0][0] = *(const short8*)(Qh + qoff); qf[0][1] = *(const short8*)(Qh + qoff + 32);
  qf[1][0] = *(const short8*)(Qm + qoff); qf[1][1] = *(const short8*)(Qm + qoff + 32);
  qf[2][0] = *(const short8*)(Ql + qoff); qf[2][1] = *(const short8*)(Ql + qoff + 32);

  f32x4 Y[4];
#pragma unroll
  for (int j = 0; j < 4; j++) Y[j] = (f32x4){0.f, 0.f, 0.f, 0.f};
  float m[4] = {-1e30f, -1e30f, -1e30f, -1e30f};
  float l[4] = {0.f, 0.f, 0.f, 0.f};

  const int r0 = tid >> 3, sg = (tid & 7) * 8;
  const int half = sg >> 5, soff = (sg & 31);

  for (int kt = 0; kt <= qt; kt++) {
    const int kb = kt * 64;
    short8 stg[12];
#pragma unroll
    for (int u = 0; u < 2; u++) {
      int row = r0 + 32 * u;
      size_t gk = ((size_t)bh * TSEQ + kb + row) * 64 + sg;
      size_t gv = ((size_t)bh * 64 + row) * TSEQ + kb + sg;
      stg[u * 6 + 0] = *(const short8*)(Kh + gk);
      stg[u * 6 + 1] = *(const short8*)(Km + gk);
      stg[u * 6 + 2] = *(const short8*)(Kl + gk);
      stg[u * 6 + 3] = *(const short8*)(Vth + gv);
      stg[u * 6 + 4] = *(const short8*)(Vtm + gv);
      stg[u * 6 + 5] = *(const short8*)(Vtl + gv);
    }
    __syncthreads();
#pragma unroll
    for (int u = 0; u < 2; u++) {
      int off = (r0 + 32 * u) * 32 + soff;
      *(short8*)(&sK[0][half][off]) = stg[u * 6 + 0];
      *(short8*)(&sK[1][half][off]) = stg[u * 6 + 1];
      *(short8*)(&sK[2][half][off]) = stg[u * 6 + 2];
      *(short8*)(&sV[0][half][off]) = stg[u * 6 + 3];
      *(short8*)(&sV[1][half][off]) = stg[u * 6 + 4];
      *(short8*)(&sV[2][half][off]) = stg[u * 6 + 5];
    }
    __syncthreads();

    f32x4 s[4];
#pragma unroll
    for (int j = 0; j < 4; j++) s[j] = (f32x4){0.f, 0.f, 0.f, 0.f};
#pragma unroll
    for (int j = 0; j < 4; j++) {
      const int ko = (16 * j + lr) * 32 + 8 * lg;
      short8 k0[3], k1[3];
#pragma unroll
      for (int lv = 0; lv < 3; lv++) {
        k0[lv] = *(const short8*)(&sK[lv][0][ko]);
        k1[lv] = *(const short8*)(&sK[lv][1][ko]);
      }
      s[j] = __builtin_amdgcn_mfma_f32_16x16x32_bf16(qf[0][0], k0[0], s[j], 0, 0, 0);
      s[j] = __builtin_amdgcn_mfma_f32_16x16x32_bf16(qf[0][1], k1[0], s[j], 0, 0, 0);
      s[j] = __builtin_amdgcn_mfma_f32_16x16x32_bf16(qf[0][0], k0[1], s[j], 0, 0, 0);
      s[j] = __builtin_amdgcn_mfma_f32_16x16x32_bf16(qf[0][1], k1[1], s[j], 0, 0, 0);
      s[j] = __builtin_amdgcn_mfma_f32_16x16x32_bf16(qf[1][0], k0[0], s[j], 0, 0, 0);
      s[j] = __builtin_amdgcn_mfma_f32_16x16x32_bf16(qf[1][1], k1[0], s[j], 0, 0, 0);
      s[j] = __builtin_amdgcn_mfma_f32_16x16x32_bf16(qf[0][0], k0[2], s[j], 0, 0, 0);
      s[j] = __builtin_amdgcn_mfma_f32_16x16x32_bf16(qf[0][1], k1[2], s[j], 0, 0, 0);
      s[j] = __builtin_amdgcn_mfma_f32_16x16x32_bf16(qf[1][0], k0[1], s[j], 0, 0, 0);
      s[j] = __builtin_amdgcn_mfma_f32_16x16x32_bf16(qf[1][1], k1[1], s[j], 0, 0, 0);
      s[j] = __builtin_amdgcn_mfma_f32_16x16x32_bf16(qf[2][0], k0[0], s[j], 0, 0, 0);
      s[j] = __builtin_amdgcn_mfma_f32_16x16x32_bf16(qf[2][1], k1[0], s[j], 0, 0, 0);
    }

    const bool diag = (kt == qt);
#pragma unroll
    for (int rr = 0; rr < 4; rr++) {
      const int q = q0 + 4 * lg + rr;
      float mx = -1e30f;
#pragma unroll
      for (int j = 0; j < 4; j++) {
        float v = s[j][rr] * 0.125f;
        if (diag && (kb + 16 * j + lr > q)) v = -1e30f;
        s[j][rr] = v;
        mx = fmaxf(mx, v);
      }
      mx = fmaxf(mx, __shfl_xor(mx, 1));
      mx = fmaxf(mx, __shfl_xor(mx, 2));
      mx = fmaxf(mx, __shfl_xor(mx, 4));
      mx = fmaxf(mx, __shfl_xor(mx, 8));
      float mn = fmaxf(m[rr], mx);
      float al = expf(m[rr] - mn);
      m[rr] = mn;
      l[rr] *= al;
#pragma unroll
      for (int j = 0; j < 4; j++) Y[j][rr] *= al;
      float ps = 0.f;
#pragma unroll
      for (int j = 0; j < 4; j++) {
        float p = expf(s[j][rr] - mn);
        s[j][rr] = p;
        ps += p;
      }
      l[rr] += ps;
    }

#pragma unroll
    for (int j = 0; j < 4; j++) {
      const int jh = j >> 1;
      const int col = 16 * (j & 1) + lr;
#pragma unroll
      for (int rr = 0; rr < 4; rr++) {
        float p = s[j][rr];
        unsigned short w0 = f2bf(p);
        float r = p - bf2f(w0);
        unsigned short w1 = f2bf(r);
        r -= bf2f(w1);
        const int o = (4 * lg + rr) * 32 + col;
        sP[0][jh][wv][o] = w0;
        sP[1][jh][wv][o] = w1;
        sP[2][jh][wv][o] = f2bf(r);
      }
    }
    __syncthreads();
    const int po = lr * 32 + 8 * lg;
    short8 pf[3][2];
#pragma unroll
    for (int lv = 0; lv < 3; lv++) {
      pf[lv][0] = *(const short8*)(&sP[lv][0][wv][po]);
      pf[lv][1] = *(const short8*)(&sP[lv][1][wv][po]);
    }
#pragma unroll
    for (int jd = 0; jd < 4; jd++) {
      const int vo = (16 * jd + lr) * 32 + 8 * lg;
      short8 v0[3], v1[3];
#pragma unroll
      for (int lv = 0; lv < 3; lv++) {
        v0[lv] = *(const short8*)(&sV[lv][0][vo]);
        v1[lv] = *(const short8*)(&sV[lv][1][vo]);
      }
      Y[jd] = __builtin_amdgcn_mfma_f32_16x16x32_bf16(pf[0][0], v0[0], Y[jd], 0, 0, 0);
      Y[jd] = __builtin_amdgcn_mfma_f32_16x16x32_bf16(pf[0][1], v1[0], Y[jd], 0, 0, 0);
      Y[jd] = __builtin_amdgcn_mfma_f32_16x16x32_bf16(pf[0][0], v0[1], Y[jd], 0, 0, 0);
      Y[jd] = __builtin_amdgcn_mfma_f32_16x16x32_bf16(pf[0][1], v1[1], Y[jd], 0, 0, 0);
      Y[jd] = __builtin_amdgcn_mfma_f32_16x16x32_bf16(pf[1][0], v0[0], Y[jd], 0, 0, 0);
      Y[jd] = __builtin_amdgcn_mfma_f32_16x16x32_bf16(pf[1][1], v1[0], Y[jd], 0, 0, 0);
      Y[jd] = __builtin_amdgcn_mfma_f32_16x16x32_bf16(pf[0][0], v0[2], Y[jd], 0, 0, 0);
      Y[jd] = __builtin_amdgcn_mfma_f32_16x16x32_bf16(pf[0][1], v1[2], Y[jd], 0, 0, 0);
      Y[jd] = __builtin_amdgcn_mfma_f32_16x16x32_bf16(pf[1][0], v0[1], Y[jd], 0, 0, 0);
      Y[jd] = __builtin_amdgcn_mfma_f32_16x16x32_bf16(pf[1][1], v1[1], Y[jd], 0, 0, 0);
      Y[jd] = __builtin_amdgcn_mfma_f32_16x16x32_bf16(pf[2][0], v0[0], Y[jd], 0, 0, 0);
      Y[jd] = __builtin_amdgcn_mfma_f32_16x16x32_bf16(pf[2][1], v1[0], Y[jd], 0, 0, 0);
    }
  }

#pragma unroll
  for (int rr = 0; rr < 4; rr++) {
    float t = l[rr];
    t += __shfl_xor(t, 1); t += __shfl_xor(t, 2);
    t += __shfl_xor(t, 4); t += __shfl_xor(t, 8);
    l[rr] = 1.0f / t;
  }
#pragma unroll
  for (int jd = 0; jd < 4; jd++) {
    const int d = 16 * jd + lr;
#pragma unroll
    for (int rr = 0; rr < 4; rr++) {
      const int q = q0 + 4 * lg + rr;
      float v = Y[jd][rr] * l[rr];
      unsigned short w0 = f2bf(v);
      const size_t ci = ((size_t)(b * TSEQ + q)) * CDIM + h * DHEAD + d;
      ath[ci] = w0;
      atl[ci] = f2bf(v - bf2f(w0));
    }
  }
}

// ---------------- LayerNorm f32 -> split hi/lo bf16 (R8 proven) ----------------
__global__ __launch_bounds__(256) void ln_split_kernel(const float* __restrict__ x,
                                                       unsigned short* __restrict__ yh,
                                                       unsigned short* __restrict__ yl,
                                                       const float* __restrict__ g,
                                                       const float* __restrict__ b) {
  int n = blockIdx.x, tid = threadIdx.x;
  const float4* xr = (const float4*)(x + (size_t)n * CDIM);
  float4 v = xr[tid];
  float s = v.x + v.y + v.z + v.w;
  float ss = v.x * v.x + v.y * v.y + v.z * v.z + v.w * v.w;
  __shared__ float rs[256], rss[256];
  rs[tid] = s; rss[tid] = ss;
  __syncthreads();
  for (int o = 128; o > 0; o >>= 1) {
    if (tid < o) { rs[tid] += rs[tid + o]; rss[tid] += rss[tid + o]; }
    __syncthreads();
  }
  float m = rs[0] * (1.0f / CDIM);
  float var = rss[0] * (1.0f / CDIM) - m * m;
  float r = rsqrtf(var + 1e-5f);
  float4 gv = ((const float4*)g)[tid];
  float4 bv = ((const float4*)b)[tid];
  float o0 = (v.x - m) * r * gv.x + bv.x;
  float o1 = (v.y - m) * r * gv.y + bv.y;
  float o2 = (v.z - m) * r * gv.z + bv.z;
  float o3 = (v.w - m) * r * gv.w + bv.w;
  ushort4 hh, ll;
  hh.x = f2bf(o0); ll.x = f2bf(o0 - bf2f(hh.x));
  hh.y = f2bf(o1); ll.y = f2bf(o1 - bf2f(hh.y));
  hh.z = f2bf(o2); ll.z = f2bf(o2 - bf2f(hh.z));
  hh.w = f2bf(o3); ll.w = f2bf(o3 - bf2f(hh.w));
  ((ushort4*)(yh + (size_t)n * CDIM))[tid] = hh;
  ((ushort4*)(yl + (size_t)n * CDIM))[tid] = ll;
}

// ---------------- f32 -> bf16 convert (R7 proven) ----------------
__global__ __launch_bounds__(256) void cvt_bf16_kernel(const float* __restrict__ x,
                                                       unsigned short* __restrict__ y) {
  int i = blockIdx.x * 256 + threadIdx.x;
  float4 v = ((const float4*)x)[i];
  ushort4 o;
  o.x = f2bf(v.x); o.y = f2bf(v.y); o.z = f2bf(v.z); o.w = f2bf(v.w);
  ((ushort4*)y)[i] = o;
}

// ---------------- LayerNorm f32 -> bf16 (R4 proven) ----------------
__global__ __launch_bounds__(256) void ln_bf16_kernel(const float* __restrict__ x,
                                                      unsigned short* __restrict__ y,
                                                      const float* __restrict__ g,
                                                      const float* __restrict__ b) {
  int n = blockIdx.x, tid = threadIdx.x;
  const float4* xr = (const float4*)(x + (size_t)n * CDIM);
  float4 v = xr[tid];
  float s = v.x + v.y + v.z + v.w;
  float ss = v.x * v.x + v.y * v.y + v.z * v.z + v.w * v.w;
  __shared__ float rs[256], rss[256];
  rs[tid] = s; rss[tid] = ss;
  __syncthreads();
  for (int o = 128; o > 0; o >>= 1) {
    if (tid < o) { rs[tid] += rs[tid + o]; rss[tid] += rss[tid + o]; }
    __syncthreads();
  }
  float m = rs[0] * (1.0f / CDIM);
  float var = rss[0] * (1.0f / CDIM) - m * m;
  float r = rsqrtf(var + 1e-5f);
  float4 gv = ((const float4*)g)[tid];
  float4 bv = ((const float4*)b)[tid];
  ushort4 o4;
  o4.x = f2bf((v.x - m) * r * gv.x + bv.x);
  o4.y = f2bf((v.y - m) * r * gv.y + bv.y);
  o4.z = f2bf((v.z - m) * r * gv.z + bv.z);
  o4.w = f2bf((v.w - m) * r * gv.w + bv.w);
  ((ushort4*)(y + (size_t)n * CDIM))[tid] = o4;
}

// ---------------- weight transpose+convert bf16, z-batched (R4 core) ----------------
__global__ __launch_bounds__(256) void wconv_t_kernel(const float* __restrict__ W,
                                                      unsigned short* __restrict__ Wt,
                                                      int K, int N,
                                                      size_t wstride, size_t ostride) {
  __shared__ float t[32][33];
  W  += (size_t)blockIdx.z * wstride;
  Wt += (size_t)blockIdx.z * ostride;
  int n0 = blockIdx.x * 32, k0 = blockIdx.y * 32;
  int tx = threadIdx.x & 31, ty = threadIdx.x >> 5;
#pragma unroll
  for (int i = 0; i < 4; i++)
    t[ty + 8 * i][tx] = W[(size_t)(k0 + ty + 8 * i) * N + n0 + tx];
  __syncthreads();
#pragma unroll
  for (int i = 0; i < 4; i++)
    Wt[(size_t)(n0 + ty + 8 * i) * K + k0 + tx] = f2bf(t[tx][ty + 8 * i]);
}

// ---------------- weight transpose + hi/lo split (R8 proven) ----------------
__global__ __launch_bounds__(256) void wconv_split_kernel(const float* __restrict__ W,
                                                          unsigned short* __restrict__ Wh,
                                                          unsigned short* __restrict__ Wl,
                                                          int K, int N) {
  __shared__ float t[32][33];
  int n0 = blockIdx.x * 32, k0 = blockIdx.y * 32;
  int tx = threadIdx.x & 31, ty = threadIdx.x >> 5;
#pragma unroll
  for (int i = 0; i < 4; i++)
    t[ty + 8 * i][tx] = W[(size_t)(k0 + ty + 8 * i) * N + n0 + tx];
  __syncthreads();
#pragma unroll
  for (int i = 0; i < 4; i++) {
    float w = t[tx][ty + 8 * i];
    unsigned short h = f2bf(w);
    size_t o = (size_t)(n0 + ty + 8 * i) * K + k0 + tx;
    Wh[o] = h;
    Wl[o] = f2bf(w - bf2f(h));
  }
}

// XCD-chunked bijective swizzle (requires gridDim.x*gridDim.y % 8 == 0)
__device__ __forceinline__ void xcd_swz(int& bx, int& by) {
  int bid = blockIdx.y * gridDim.x + blockIdx.x;
  int cpx = (gridDim.x * gridDim.y) >> 3;
  bid = (bid & 7) * cpx + (bid >> 3);
  bx = bid % gridDim.x;
  by = bid / gridDim.x;
}

// ---------------- split-bf16 MFMA GEMM, global_load_lds staging ----------------
// MODE 0: C=v   1: gelu(v+bias) -> split Ch,Cl   2: C+=v   3: C+=v+bias
template <int MODE>
__global__ __launch_bounds__(256) void gemm_split(const unsigned short* __restrict__ Ah,
                                                  const unsigned short* __restrict__ Al,
                                                  const unsigned short* __restrict__ Bth,
                                                  const unsigned short* __restrict__ Btl,
                                                  float* __restrict__ C,
                                                  unsigned short* __restrict__ Ch,
                                                  unsigned short* __restrict__ Cl,
                                                  const float* __restrict__ bias,
                                                  int M, int Nn, int K) {
  __shared__ __align__(16) unsigned short AsH[128 * 32];
  __shared__ __align__(16) unsigned short AsL[128 * 32];
  __shared__ __align__(16) unsigned short BsH[128 * 32];
  __shared__ __align__(16) unsigned short BsL[128 * 32];
  const int tid = threadIdx.x;
  const int wv = tid >> 6, ln = tid & 63;
  int sbx, sby;
  xcd_swz(sbx, sby);
  const int bm = sby * 128, bn = sbx * 128;

  const size_t aoff0 = (size_t)(bm + 32 * wv + (ln >> 2)) * K + (size_t)((ln & 3) * 8);
  const size_t aoff1 = aoff0 + (size_t)16 * K;
  const size_t boff0 = (size_t)(bn + 32 * wv + (ln >> 2)) * K + (size_t)((ln & 3) * 8);
  const size_t boff1 = boff0 + (size_t)16 * K;
  unsigned short* lA = AsH + 1024 * wv;    // wave-uniform LDS bases
  unsigned short* lAl = AsL + 1024 * wv;
  unsigned short* lB = BsH + 1024 * wv;
  unsigned short* lBl = BsL + 1024 * wv;

  const int wm = wv >> 1, wn = wv & 1;
  const int lr = ln & 15, lg = ln >> 4;

  f32x4 acc[4][4];
#pragma unroll
  for (int i = 0; i < 4; i++)
#pragma unroll
    for (int j = 0; j < 4; j++) acc[i][j] = (f32x4){0.f, 0.f, 0.f, 0.f};

  for (int k0 = 0; k0 < K; k0 += 32) {
    GLDS(Ah + aoff0 + k0, lA);
    GLDS(Ah + aoff1 + k0, lA + 512);
    GLDS(Al + aoff0 + k0, lAl);
    GLDS(Al + aoff1 + k0, lAl + 512);
    GLDS(Bth + boff0 + k0, lB);
    GLDS(Bth + boff1 + k0, lB + 512);
    GLDS(Btl + boff0 + k0, lBl);
    GLDS(Btl + boff1 + k0, lBl + 512);
    __syncthreads();

    short8 afh[4], afl[4], bwh[4], bwl[4];
#pragma unroll
    for (int i = 0; i < 4; i++) {
      const int ao = (64 * wm + 16 * i + lr) * 32 + 8 * lg;
      afh[i] = *(const short8*)(AsH + ao);
      afl[i] = *(const short8*)(AsL + ao);
    }
#pragma unroll
    for (int j = 0; j < 4; j++) {
      const int bo = (64 * wn + 16 * j + lr) * 32 + 8 * lg;
      bwh[j] = *(const short8*)(BsH + bo);
      bwl[j] = *(const short8*)(BsL + bo);
    }
#pragma unroll
    for (int i = 0; i < 4; i++)
#pragma unroll
      for (int j = 0; j < 4; j++) {
        acc[i][j] = __builtin_amdgcn_mfma_f32_16x16x32_bf16(afh[i], bwh[j], acc[i][j], 0, 0, 0);
        acc[i][j] = __builtin_amdgcn_mfma_f32_16x16x32_bf16(afl[i], bwh[j], acc[i][j], 0, 0, 0);
        acc[i][j] = __builtin_amdgcn_mfma_f32_16x16x32_bf16(afh[i], bwl[j], acc[i][j], 0, 0, 0);
      }
    __syncthreads();
  }

#pragma unroll
  for (int j = 0; j < 4; j++) {
    const int n = bn + 64 * wn + 16 * j + lr;
    const float bb = (MODE == 1 || MODE == 3) ? bias[n] : 0.0f;
#pragma unroll
    for (int i = 0; i < 4; i++) {
#pragma unroll
      for (int rr = 0; rr < 4; rr++) {
        const int m = bm + 64 * wm + 16 * i + 4 * lg + rr;
        float v = acc[i][j][rr];
        const size_t ci = (size_t)m * Nn + n;
        if constexpr (MODE == 0) {
          C[ci] = v;
        } else if constexpr (MODE == 1) {
          v += bb;
          v = 0.5f * v * (1.0f + erff(v * 0.70710678118654752f));
          unsigned short h = f2bf(v);
          Ch[ci] = h;
          Cl[ci] = f2bf(v - bf2f(h));
        } else if constexpr (MODE == 2) {
          C[ci] += v;
        } else {
          C[ci] += v + bb;
        }
      }
    }
  }
}

// ---------------- bf16 MFMA GEMM, global_load_lds staging (head) ----------------
__global__ __launch_bounds__(256) void gemm_bf16(const unsigned short* __restrict__ A,
                                                 const unsigned short* __restrict__ Bt,
                                                 float* __restrict__ C,
                                                 int M, int Nn, int K) {
  __shared__ __align__(16) unsigned short As[128 * 32];
  __shared__ __align__(16) unsigned short Bs[128 * 32];
  const int tid = threadIdx.x;
  const int wv = tid >> 6, ln = tid & 63;
  int sbx, sby;
  xcd_swz(sbx, sby);
  const int bm = sby * 128, bn = sbx * 128;

  const size_t aoff0 = (size_t)(bm + 32 * wv + (ln >> 2)) * K + (size_t)((ln & 3) * 8);
  const size_t aoff1 = aoff0 + (size_t)16 * K;
  const size_t boff0 = (size_t)(bn + 32 * wv + (ln >> 2)) * K + (size_t)((ln & 3) * 8);
  const size_t boff1 = boff0 + (size_t)16 * K;
  unsigned short* lA = As + 1024 * wv;
  unsigned short* lB = Bs + 1024 * wv;

  const int wm = wv >> 1, wn = wv & 1;
  const int lr = ln & 15, lg = ln >> 4;

  f32x4 acc[4][4];
#pragma unroll
  for (int i = 0; i < 4; i++)
#pragma unroll
    for (int j = 0; j < 4; j++) acc[i][j] = (f32x4){0.f, 0.f, 0.f, 0.f};

  for (int k0 = 0; k0 < K; k0 += 32) {
    GLDS(A + aoff0 + k0, lA);
    GLDS(A + aoff1 + k0, lA + 512);
    GLDS(Bt + boff0 + k0, lB);
    GLDS(Bt + boff1 + k0, lB + 512);
    __syncthreads();

    short8 af[4], bw[4];
#pragma unroll
    for (int i = 0; i < 4; i++)
      af[i] = *(const short8*)(As + ((64 * wm + 16 * i + lr) * 32 + 8 * lg));
#pragma unroll
    for (int j = 0; j < 4; j++)
      bw[j] = *(const short8*)(Bs + ((64 * wn + 16 * j + lr) * 32 + 8 * lg));
#pragma unroll
    for (int i = 0; i < 4; i++)
#pragma unroll
      for (int j = 0; j < 4; j++)
        acc[i][j] = __builtin_amdgcn_mfma_f32_16x16x32_bf16(af[i], bw[j], acc[i][j], 0, 0, 0);
    __syncthreads();
  }

#pragma unroll
  for (int j = 0; j < 4; j++) {
    const int n = bn + 64 * wn + 16 * j + lr;
#pragma unroll
    for (int i = 0; i < 4; i++) {
#pragma unroll
      for (int r = 0; r < 4; r++) {
        const int m = bm + 64 * wm + 16 * i + 4 * lg + r;
        C[(size_t)m * Nn + n] = acc[i][j][r];
      }
    }
  }
}

// ---------------- batched sparse MoE GEMM 1 (z = expert): gather-A, gelu out ----------------
__global__ __launch_bounds__(256) void gemm_moe1(const unsigned short* __restrict__ A,
                                                 const unsigned short* __restrict__ BtAll,
                                                 unsigned short* __restrict__ CuAll,
                                                 const float* __restrict__ biasAll,
                                                 const int* __restrict__ cntAll,
                                                 const int* __restrict__ lstAll,
                                                 int Nn, int K) {
  const int e = blockIdx.z;
  const int ce = cntAll[e];
  const int bm = blockIdx.y * 128, bn = blockIdx.x * 128;
  if (bm >= ce) return;
  const unsigned short* Bt = BtAll + (size_t)e * Nn * K;
  unsigned short* Cu = CuAll + (size_t)e * NTOK * Nn;
  const float* bias = biasAll + (size_t)e * Nn;
  const int* lst = lstAll + (size_t)e * NTOK;

  __shared__ __align__(16) unsigned short As[128 * 32];
  __shared__ __align__(16) unsigned short Bs[128 * 32];
  const int tid = threadIdx.x;
  const int wv = tid >> 6, ln = tid & 63;

  const int ra = bm + 32 * wv + (ln >> 2);
  const int t0 = lst[(ra      < ce) ? ra      : 0];
  const int t1 = lst[(ra + 16 < ce) ? ra + 16 : 0];
  const size_t aoff0 = (size_t)t0 * K + (size_t)((ln & 3) * 8);
  const size_t aoff1 = (size_t)t1 * K + (size_t)((ln & 3) * 8);
  const size_t boff0 = (size_t)(bn + 32 * wv + (ln >> 2)) * K + (size_t)((ln & 3) * 8);
  const size_t boff1 = boff0 + (size_t)16 * K;
  unsigned short* lA = As + 1024 * wv;
  unsigned short* lB = Bs + 1024 * wv;

  const int wm = wv >> 1, wn = wv & 1;
  const int lr = ln & 15, lg = ln >> 4;

  f32x4 acc[4][4];
#pragma unroll
  for (int i = 0; i < 4; i++)
#pragma unroll
    for (int j = 0; j < 4; j++) acc[i][j] = (f32x4){0.f, 0.f, 0.f, 0.f};

  for (int k0 = 0; k0 < K; k0 += 32) {
    GLDS(A + aoff0 + k0, lA);
    GLDS(A + aoff1 + k0, lA + 512);
    GLDS(Bt + boff0 + k0, lB);
    GLDS(Bt + boff1 + k0, lB + 512);
    __syncthreads();

    short8 af[4], bw[4];
#pragma unroll
    for (int i = 0; i < 4; i++)
      af[i] = *(const short8*)(As + ((64 * wm + 16 * i + lr) * 32 + 8 * lg));
#pragma unroll
    for (int j = 0; j < 4; j++)
      bw[j] = *(const short8*)(Bs + ((64 * wn + 16 * j + lr) * 32 + 8 * lg));
#pragma unroll
    for (int i = 0; i < 4; i++)
#pragma unroll
      for (int j = 0; j < 4; j++)
        acc[i][j] = __builtin_amdgcn_mfma_f32_16x16x32_bf16(af[i], bw[j], acc[i][j], 0, 0, 0);
    __syncthreads();
  }

#pragma unroll
  for (int j = 0; j < 4; j++) {
    const int n = bn + 64 * wn + 16 * j + lr;
    const float bb = bias[n];
#pragma unroll
    for (int i = 0; i < 4; i++) {
#pragma unroll
      for (int r = 0; r < 4; r++) {
        const int m = bm + 64 * wm + 16 * i + 4 * lg + r;
        float v = acc[i][j][r] + bb;
        v = 0.5f * v * (1.0f + erff(v * 0.70710678118654752f));
        Cu[(size_t)m * Nn + n] = f2bf(v);
      }
    }
  }
}

// ---------------- batched sparse MoE GEMM 2 (z = expert): atomic scatter out ----------------
__global__ __launch_bounds__(256) void gemm_moe2(const unsigned short* __restrict__ AAll,
                                                 const unsigned short* __restrict__ BtAll,
                                                 float* __restrict__ C,
                                                 const float* __restrict__ biasAll,
                                                 const int* __restrict__ cntAll,
                                                 const int* __restrict__ lstAll,
                                                 const float* __restrict__ wtsAll,
                                                 int Nn, int K) {
  const int e = blockIdx.z;
  const int ce = cntAll[e];
  const int bm = blockIdx.y * 128, bn = blockIdx.x * 128;
  if (bm >= ce) return;
  const unsigned short* A = AAll + (size_t)e * NTOK * K;
  const unsigned short* Bt = BtAll + (size_t)e * Nn * K;
  const float* bias = biasAll + (size_t)e * Nn;
  const int* lst = lstAll + (size_t)e * NTOK;
  const float* wts = wtsAll + (size_t)e * NTOK;

  __shared__ __align__(16) unsigned short As[128 * 32];
  __shared__ __align__(16) unsigned short Bs[128 * 32];
  const int tid = threadIdx.x;
  const int wv = tid >> 6, ln = tid & 63;

  const size_t aoff0 = (size_t)(bm + 32 * wv + (ln >> 2)) * K + (size_t)((ln & 3) * 8);
  const size_t aoff1 = aoff0 + (size_t)16 * K;
  const size_t boff0 = (size_t)(bn + 32 * wv + (ln >> 2)) * K + (size_t)((ln & 3) * 8);
  const size_t boff1 = boff0 + (size_t)16 * K;
  unsigned short* lA = As + 1024 * wv;
  unsigned short* lB = Bs + 1024 * wv;

  const int wm = wv >> 1, wn = wv & 1;
  const int lr = ln & 15, lg = ln >> 4;

  f32x4 acc[4][4];
#pragma unroll
  for (int i = 0; i < 4; i++)
#pragma unroll
    for (int j = 0; j < 4; j++) acc[i][j] = (f32x4){0.f, 0.f, 0.f, 0.f};

  for (int k0 = 0; k0 < K; k0 += 32) {
    GLDS(A + aoff0 + k0, lA);
    GLDS(A + aoff1 + k0, lA + 512);
    GLDS(Bt + boff0 + k0, lB);
    GLDS(Bt + boff1 + k0, lB + 512);
    __syncthreads();

    short8 af[4], bw[4];
#pragma unroll
    for (int i = 0; i < 4; i++)
      af[i] = *(const short8*)(As + ((64 * wm + 16 * i + lr) * 32 + 8 * lg));
#pragma unroll
    for (int j = 0; j < 4; j++)
      bw[j] = *(const short8*)(Bs + ((64 * wn + 16 * j + lr) * 32 + 8 * lg));
#pragma unroll
    for (int i = 0; i < 4; i++)
#pragma unroll
      for (int j = 0; j < 4; j++)
        acc[i][j] = __builtin_amdgcn_mfma_f32_16x16x32_bf16(af[i], bw[j], acc[i][j], 0, 0, 0);
    __syncthreads();
  }

#pragma unroll
  for (int j = 0; j < 4; j++) {
    const int n = bn + 64 * wn + 16 * j + lr;
    const float bb = bias[n];
#pragma unroll
    for (int i = 0; i < 4; i++) {
#pragma unroll
      for (int r = 0; r < 4; r++) {
        const int m = bm + 64 * wm + 16 * i + 4 * lg + r;
        if (m < ce) {
          const int tok = lst[m];
          atomicAdd(&C[(size_t)tok * Nn + n], wts[m] * (acc[i][j][r] + bb));
        }
      }
    }
  }
}

// ---------------- router -> per-expert token lists (R15 proven) ----------------
__global__ __launch_bounds__(64) void router2_kernel(const float* __restrict__ x,
                                                     const float* __restrict__ rw,
                                                     int* __restrict__ cnt,
                                                     int* __restrict__ lst,
                                                     float* __restrict__ wts) {
  int n = blockIdx.x, lane = threadIdx.x;
  const float* xr = x + (size_t)n * CDIM;
  float acc[NEXP] = {};
  for (int i = 0; i < CDIM / 64; i++) {
    int c = lane + 64 * i;
    float xv = xr[c];
    const float* r = rw + (size_t)c * NEXP;
#pragma unroll
    for (int e = 0; e < NEXP; e++) acc[e] += xv * r[e];
  }
  for (int m = 32; m >= 1; m >>= 1)
#pragma unroll
    for (int e = 0; e < NEXP; e++) acc[e] += __shfl_xor(acc[e], m);
  if (lane == 0) {
    float mx = acc[0];
#pragma unroll
    for (int e = 1; e < NEXP; e++) mx = fmaxf(mx, acc[e]);
    float p[NEXP];
#pragma unroll
    for (int e = 0; e < NEXP; e++) p[e] = expf(acc[e] - mx);
    int i1 = 0;
#pragma unroll
    for (int e = 1; e < NEXP; e++) if (p[e] > p[i1]) i1 = e;
    int i2 = (i1 == 0) ? 1 : 0;
#pragma unroll
    for (int e = 0; e < NEXP; e++) if (e != i1 && p[e] > p[i2]) i2 = e;
    float denom = p[i1] + p[i2];
    int p1 = atomicAdd(&cnt[i1], 1);
    lst[i1 * NTOK + p1] = n;
    wts[i1 * NTOK + p1] = p[i1] / denom;
    int p2 = atomicAdd(&cnt[i2], 1);
    lst[i2 * NTOK + p2] = n;
    wts[i2 * NTOK + p2] = p[i2] / denom;
  }
}

extern "C" void kernel_launch(void* const* d_in, const int* in_sizes, int n_in,
                              void* d_out, int out_size, void* d_ws, size_t ws_size,
                              hipStream_t stream) {
  const int*   idx      = (const int*)d_in[0];
  const float* tok_emb  = (const float*)d_in[1];
  const float* ln1_g    = (const float*)d_in[2];
  const float* ln1_b    = (const float*)d_in[3];
  const float* ln2_g    = (const float*)d_in[4];
  const float* ln2_b    = (const float*)d_in[5];
  const float* qkv_w    = (const float*)d_in[6];
  const float* proj_w   = (const float*)d_in[7];
  const float* ff_w1    = (const float*)d_in[8];
  const float* ff_b1    = (const float*)d_in[9];
  const float* ff_w2    = (const float*)d_in[10];
  const float* ff_b2    = (const float*)d_in[11];
  const float* router_w = (const float*)d_in[12];
  const float* exp_w1   = (const float*)d_in[13];
  const float* exp_b1   = (const float*)d_in[14];
  const float* exp_w2   = (const float*)d_in[15];
  const float* exp_b2   = (const float*)d_in[16];
  const float* lnf_g    = (const float*)d_in[17];
  const float* lnf_b    = (const float*)d_in[18];
  const float* head_w   = (const float*)d_in[19];
  float* out = (float*)d_out;

  // ---- workspace layout (~144 MB) ----
  const size_t NC = (size_t)NTOK * CDIM;
  char* w = (char*)d_ws;
  float* x  = (float*)w;                 w += NC * 4;
  unsigned short* S1 = (unsigned short*)w; w += NC * 4;
  float* Q  = (float*)w;                 w += (size_t)NTOK * C3 * 4;
  float* C3r = (float*)w;                w += NC * 4;
  unsigned short* WS = (unsigned short*)w; w += NC * 4;
  unsigned short* EX = (unsigned short*)w; w += NC * 6;
  float* ct = (float*)w;                 w += (size_t)TSEQ * 32 * 4;
  float* st = (float*)w;                 w += (size_t)TSEQ * 32 * 4;
  int*   moe_cnt = (int*)w;              w += NEXP * 4;
  int*   moe_lst = (int*)w;              w += (size_t)NEXP * NTOK * 4;
  float* moe_wts = (float*)w;            w += (size_t)NEXP * NTOK * 4;

  // trunk aliases
  unsigned short* xh = S1;
  unsigned short* xl = S1 + NC;
  unsigned short* Wh = WS;
  unsigned short* Wl = WS + NC;
  float* qkvf = Q;
  // attention-phase aliases
  unsigned short* Qh_s = S1;
  unsigned short* Qm_s = S1 + NC;
  unsigned short* Ql_s = EX;
  unsigned short* Kh_s = (unsigned short*)C3r;
  unsigned short* Km_s = (unsigned short*)C3r + NC;
  unsigned short* Kl_s = EX + NC;
  unsigned short* Vth_s = WS;
  unsigned short* Vtm_s = WS + NC;
  unsigned short* Vtl_s = EX + 2 * NC;
  unsigned short* ath = (unsigned short*)Q;
  unsigned short* atl = (unsigned short*)Q + NC;
  // FF aliases
  unsigned short* hh = (unsigned short*)Q;
  unsigned short* hl = (unsigned short*)Q + (size_t)NTOK * FFDIM;
  // MoE aliases (batched)
  unsigned short* x_bf   = S1;
  unsigned short* exp1t  = EX;
  unsigned short* exp2t  = WS;
  unsigned short* hmoeC  = (unsigned short*)Q;      // [NEXP][NTOK][DEXP] bf16, 64MB
  float* moe_out  = x;
  // head aliases
  unsigned short* xn_bf   = S1;
  unsigned short* wt_head = (unsigned short*)Q;

  embed_kernel<<<NTOK, 256, 0, stream>>>(idx, tok_emb, x);
  rope_table_kernel<<<TSEQ, 32, 0, stream>>>(ct, st);

  for (int l = 0; l < LAYERS; l++) {
    // --- attention sublayer ---
    ln_split_kernel<<<NTOK, 256, 0, stream>>>(x, xh, xl, ln1_g + l * CDIM, ln1_b + l * CDIM);
    wconv_split_kernel<<<dim3(C3 / 32, CDIM / 32), 256, 0, stream>>>(
        qkv_w + (size_t)l * CDIM * C3, Wh, Wl, CDIM, C3);
    gemm_split<0><<<dim3(C3 / 128, NTOK / 128), 256, 0, stream>>>(
        xh, xl, Wh, Wl, qkvf, nullptr, nullptr, nullptr, NTOK, C3, CDIM);
    qkv_prep_kernel<<<dim3(TSEQ / 64, HEADS, 8), 256, 0, stream>>>(
        qkvf, ct, st, Qh_s, Qm_s, Ql_s, Kh_s, Km_s, Kl_s, Vth_s, Vtm_s, Vtl_s);
    flash_attn_kernel<<<dim3(TSEQ / 64, HEADS, 8), 256, 0, stream>>>(
        Qh_s, Qm_s, Ql_s, Kh_s, Km_s, Kl_s, Vth_s, Vtm_s, Vtl_s, ath, atl);
    wconv_split_kernel<<<dim3(CDIM / 32, CDIM / 32), 256, 0, stream>>>(
        proj_w + (size_t)l * CDIM * CDIM, Wh, Wl, CDIM, CDIM);
    gemm_split<2><<<dim3(CDIM / 128, NTOK / 128), 256, 0, stream>>>(
        ath, atl, Wh, Wl, x, nullptr, nullptr, nullptr, NTOK, CDIM, CDIM);
    // --- FF sublayer ---
    ln_split_kernel<<<NTOK, 256, 0, stream>>>(x, xh, xl, ln2_g + l * CDIM, ln2_b + l * CDIM);
    wconv_split_kernel<<<dim3(FFDIM / 32, CDIM / 32), 256, 0, stream>>>(
        ff_w1 + (size_t)l * CDIM * FFDIM, Wh, Wl, CDIM, FFDIM);
    gemm_split<1><<<dim3(FFDIM / 128, NTOK / 128), 256, 0, stream>>>(
        xh, xl, Wh, Wl, nullptr, hh, hl, ff_b1 + (size_t)l * FFDIM, NTOK, FFDIM, CDIM);
    wconv_split_kernel<<<dim3(CDIM / 32, FFDIM / 32), 256, 0, stream>>>(
        ff_w2 + (size_t)l * FFDIM * CDIM, Wh, Wl, FFDIM, CDIM);
    gemm_split<3><<<dim3(CDIM / 128, NTOK / 128), 256, 0, stream>>>(
        hh, hl, Wh, Wl, x, nullptr, nullptr, ff_b2 + (size_t)l * CDIM, NTOK, CDIM, FFDIM);
  }

  // --- batched sparse top-2 MoE ---
  hipMemsetAsync(moe_cnt, 0, NEXP * sizeof(int), stream);
  router2_kernel<<<NTOK, 64, 0, stream>>>(x, router_w, moe_cnt, moe_lst, moe_wts);
  cvt_bf16_kernel<<<(NC / 4) / 256, 256, 0, stream>>>(x, x_bf);
  wconv_t_kernel<<<dim3(DEXP / 32, CDIM / 32, NEXP), 256, 0, stream>>>(
      exp_w1, exp1t, CDIM, DEXP, (size_t)CDIM * DEXP, (size_t)CDIM * DEXP);
  wconv_t_kernel<<<dim3(CDIM / 32, DEXP / 32, NEXP), 256, 0, stream>>>(
      exp_w2, exp2t, DEXP, CDIM, (size_t)DEXP * CDIM, (size_t)DEXP * CDIM);
  gemm_moe1<<<dim3(DEXP / 128, NTOK / 128, NEXP), 256, 0, stream>>>(
      x_bf, exp1t, hmoeC, exp_b1, moe_cnt, moe_lst, DEXP, CDIM);
  hipMemsetAsync(moe_out, 0, NC * sizeof(float), stream);
  gemm_moe2<<<dim3(CDIM / 128, NTOK / 128, NEXP), 256, 0, stream>>>(
      hmoeC, exp2t, moe_out, exp_b2, moe_cnt, moe_lst, moe_wts, CDIM, DEXP);

  // --- head ---
  ln_bf16_kernel<<<NTOK, 256, 0, stream>>>(moe_out, xn_bf, lnf_g, lnf_b);
  wconv_t_kernel<<<dim3(VOCAB / 32, CDIM / 32, 1), 256, 0, stream>>>(
      head_w, wt_head, CDIM, VOCAB, 0, 0);
  gemm_bf16<<<dim3(VOCAB / 128, NTOK / 128), 256, 0, stream>>>(
      xn_bf, wt_head, out, NTOK, VOCAB, CDIM);
}

// Round 18
// 2469.996 us; speedup vs baseline: 1.0245x; 1.0245x over previous
//
#include <hip/hip_runtime.h>
#include <math.h>

// MoE-GPT forward, round 18: REVERT to R16 (best verified: 2470 us).
// R17's global_load_lds swap exposed full HBM latency per K-step (loads
// issued immediately before barrier = no prefetch overlap) and regressed.
// R16 = reg-staged LDS GEMMs + XCD swizzle + fused epilogues + 3-way-split
// flash attention + batched sparse top-2 MoE.

#define NTOK  4096
#define CDIM  1024
#define HEADS 16
#define DHEAD 64
#define LAYERS 3
#define NEXP  8
#define DEXP  1024
#define TSEQ  512
#define FFDIM 4096
#define VOCAB 32000
#define C3    3072

typedef __attribute__((ext_vector_type(8))) short short8;
typedef __attribute__((ext_vector_type(4))) float f32x4;

__device__ __forceinline__ unsigned short f2bf(float f) {
  unsigned int u = __builtin_bit_cast(unsigned int, f);
  return (unsigned short)((u + 0x7fffu + ((u >> 16) & 1u)) >> 16);  // RNE
}
__device__ __forceinline__ float bf2f(unsigned short h) {
  return __builtin_bit_cast(float, ((unsigned int)h) << 16);
}

// ---------------- embedding gather ----------------
__global__ __launch_bounds__(256) void embed_kernel(const int* __restrict__ idx,
                                                    const float* __restrict__ emb,
                                                    float* __restrict__ x) {
  int i = blockIdx.x * 256 + threadIdx.x;
  int n = i >> 8, c4 = i & 255;
  const float4* src = (const float4*)(emb + (size_t)idx[n] * CDIM);
  ((float4*)(x + (size_t)n * CDIM))[c4] = src[c4];
}

// ---------------- RoPE cos/sin table [T][32] ----------------
__global__ void rope_table_kernel(float* __restrict__ ct, float* __restrict__ st) {
  int t = blockIdx.x, p = threadIdx.x;
  float inv = powf(10000.0f, -(float)p / 32.0f);
  float ang = (float)t * inv;
  ct[t * 32 + p] = cosf(ang);
  st[t * 32 + p] = sinf(ang);
}

// ---------------- qkv prep: RoPE + 3-way split + head-major relayout (R13 proven) ----------------
__global__ __launch_bounds__(256) void qkv_prep_kernel(
    const float* __restrict__ qkv, const float* __restrict__ ct,
    const float* __restrict__ st,
    unsigned short* __restrict__ Qh, unsigned short* __restrict__ Qm,
    unsigned short* __restrict__ Ql,
    unsigned short* __restrict__ Kh, unsigned short* __restrict__ Km,
    unsigned short* __restrict__ Kl,
    unsigned short* __restrict__ Vth, unsigned short* __restrict__ Vtm,
    unsigned short* __restrict__ Vtl) {
  __shared__ unsigned short sVh[64 * 64], sVm[64 * 64], sVl[64 * 64];  // [d][t]
  const int tid = threadIdx.x;
  const int tt0 = blockIdx.x * 64, h = blockIdx.y, b = blockIdx.z;
  const int bh = b * HEADS + h;
#pragma unroll
  for (int u = 0; u < 8; u++) {
    int pidx = tid + u * 256;
    int tl = pidx >> 5, p = pidx & 31;
    int t = tt0 + tl;
    size_t nb = ((size_t)(b * TSEQ + t)) * C3 + h * DHEAD;
    float c0 = ct[t * 32 + p], s0 = st[t * 32 + p];
    size_t ob = ((size_t)bh * TSEQ + t) * 64;
    float a = qkv[nb + p], bb = qkv[nb + p + 32];
    float lo = a * c0 - bb * s0, hi = bb * c0 + a * s0;
    unsigned short w0, w1;
    float r;
    w0 = f2bf(lo); r = lo - bf2f(w0); w1 = f2bf(r); r -= bf2f(w1);
    Qh[ob + p] = w0; Qm[ob + p] = w1; Ql[ob + p] = f2bf(r);
    w0 = f2bf(hi); r = hi - bf2f(w0); w1 = f2bf(r); r -= bf2f(w1);
    Qh[ob + p + 32] = w0; Qm[ob + p + 32] = w1; Ql[ob + p + 32] = f2bf(r);
    a = qkv[nb + CDIM + p]; bb = qkv[nb + CDIM + p + 32];
    lo = a * c0 - bb * s0; hi = bb * c0 + a * s0;
    w0 = f2bf(lo); r = lo - bf2f(w0); w1 = f2bf(r); r -= bf2f(w1);
    Kh[ob + p] = w0; Km[ob + p] = w1; Kl[ob + p] = f2bf(r);
    w0 = f2bf(hi); r = hi - bf2f(w0); w1 = f2bf(r); r -= bf2f(w1);
    Kh[ob + p + 32] = w0; Km[ob + p + 32] = w1; Kl[ob + p + 32] = f2bf(r);
  }
#pragma unroll
  for (int u = 0; u < 4; u++) {
    int vidx = tid + u * 256;
    int tl = vidx >> 4, d4 = (vidx & 15) * 4;
    int t = tt0 + tl;
    float4 v = *(const float4*)(qkv + ((size_t)(b * TSEQ + t)) * C3 + 2 * CDIM + h * DHEAD + d4);
    float vv[4] = {v.x, v.y, v.z, v.w};
#pragma unroll
    for (int j = 0; j < 4; j++) {
      unsigned short w0 = f2bf(vv[j]);
      float r = vv[j] - bf2f(w0);
      unsigned short w1 = f2bf(r);
      r -= bf2f(w1);
      sVh[(d4 + j) * 64 + tl] = w0;
      sVm[(d4 + j) * 64 + tl] = w1;
      sVl[(d4 + j) * 64 + tl] = f2bf(r);
    }
  }
  __syncthreads();
#pragma unroll
  for (int u = 0; u < 2; u++) {
    int idx = tid + u * 256;
    int d = idx >> 3, seg = (idx & 7) * 8;
    size_t go = ((size_t)bh * 64 + d) * TSEQ + tt0 + seg;
    *(short8*)(Vth + go) = *(const short8*)(sVh + d * 64 + seg);
    *(short8*)(Vtm + go) = *(const short8*)(sVm + d * 64 + seg);
    *(short8*)(Vtl + go) = *(const short8*)(sVl + d * 64 + seg);
  }
}

// ---------------- flash attention, 3-way split (R13/R14 proven), split output ----------------
__global__ __launch_bounds__(256) void flash_attn_kernel(
    const unsigned short* __restrict__ Qh, const unsigned short* __restrict__ Qm,
    const unsigned short* __restrict__ Ql,
    const unsigned short* __restrict__ Kh, const unsigned short* __restrict__ Km,
    const unsigned short* __restrict__ Kl,
    const unsigned short* __restrict__ Vth, const unsigned short* __restrict__ Vtm,
    const unsigned short* __restrict__ Vtl,
    unsigned short* __restrict__ ath, unsigned short* __restrict__ atl) {
  __shared__ __align__(16) unsigned short sK[3][2][64 * 32];
  __shared__ __align__(16) unsigned short sV[3][2][64 * 32];
  __shared__ __align__(16) unsigned short sP[3][2][4][16 * 32];
  const int tid = threadIdx.x;
  const int wv = tid >> 6, ln = tid & 63;
  const int qt = blockIdx.x, h = blockIdx.y, b = blockIdx.z;
  const int bh = b * HEADS + h;
  const int lr = ln & 15, lg = ln >> 4;
  const int q0 = qt * 64 + wv * 16;

  const size_t qoff = ((size_t)bh * TSEQ + q0 + lr) * 64 + 8 * lg;
  short8 qf[3][2];
  qf[0][0] = *(const short8*)(Qh + qoff); qf[0][1] = *(const short8*)(Qh + qoff + 32);
  qf[1][0] = *(const short8*)(Qm + qoff); qf[1][1] = *(const short8*)(Qm + qoff + 32);
  qf[2][0] = *(const short8*)(Ql + qoff); qf[2][1] = *(const short8*)(Ql + qoff + 32);

  f32x4 Y[4];
#pragma unroll
  for (int j = 0; j < 4; j++) Y[j] = (f32x4){0.f, 0.f, 0.f, 0.f};
  float m[4] = {-1e30f, -1e30f, -1e30f, -1e30f};
  float l[4] = {0.f, 0.f, 0.f, 0.f};

  const int r0 = tid >> 3, sg = (tid & 7) * 8;
  const int half = sg >> 5, soff = (sg & 31);

  for (int kt = 0; kt <= qt; kt++) {
    const int kb = kt * 64;
    short8 stg[12];
#pragma unroll
    for (int u = 0; u < 2; u++) {
      int row = r0 + 32 * u;
      size_t gk = ((size_t)bh * TSEQ + kb + row) * 64 + sg;
      size_t gv = ((size_t)bh * 64 + row) * TSEQ + kb + sg;
      stg[u * 6 + 0] = *(const short8*)(Kh + gk);
      stg[u * 6 + 1] = *(const short8*)(Km + gk);
      stg[u * 6 + 2] = *(const short8*)(Kl + gk);
      stg[u * 6 + 3] = *(const short8*)(Vth + gv);
      stg[u * 6 + 4] = *(const short8*)(Vtm + gv);
      stg[u * 6 + 5] = *(const short8*)(Vtl + gv);
    }
    __syncthreads();
#pragma unroll
    for (int u = 0; u < 2; u++) {
      int off = (r0 + 32 * u) * 32 + soff;
      *(short8*)(&sK[0][half][off]) = stg[u * 6 + 0];
      *(short8*)(&sK[1][half][off]) = stg[u * 6 + 1];
      *(short8*)(&sK[2][half][off]) = stg[u * 6 + 2];
      *(short8*)(&sV[0][half][off]) = stg[u * 6 + 3];
      *(short8*)(&sV[1][half][off]) = stg[u * 6 + 4];
      *(short8*)(&sV[2][half][off]) = stg[u * 6 + 5];
    }
    __syncthreads();

    f32x4 s[4];
#pragma unroll
    for (int j = 0; j < 4; j++) s[j] = (f32x4){0.f, 0.f, 0.f, 0.f};
#pragma unroll
    for (int j = 0; j < 4; j++) {
      const int ko = (16 * j + lr) * 32 + 8 * lg;
      short8 k0[3], k1[3];
#pragma unroll
      for (int lv = 0; lv < 3; lv++) {
        k0[lv] = *(const short8*)(&sK[lv][0][ko]);
        k1[lv] = *(const short8*)(&sK[lv][1][ko]);
      }
      s[j] = __builtin_amdgcn_mfma_f32_16x16x32_bf16(qf[0][0], k0[0], s[j], 0, 0, 0);
      s[j] = __builtin_amdgcn_mfma_f32_16x16x32_bf16(qf[0][1], k1[0], s[j], 0, 0, 0);
      s[j] = __builtin_amdgcn_mfma_f32_16x16x32_bf16(qf[0][0], k0[1], s[j], 0, 0, 0);
      s[j] = __builtin_amdgcn_mfma_f32_16x16x32_bf16(qf[0][1], k1[1], s[j], 0, 0, 0);
      s[j] = __builtin_amdgcn_mfma_f32_16x16x32_bf16(qf[1][0], k0[0], s[j], 0, 0, 0);
      s[j] = __builtin_amdgcn_mfma_f32_16x16x32_bf16(qf[1][1], k1[0], s[j], 0, 0, 0);
      s[j] = __builtin_amdgcn_mfma_f32_16x16x32_bf16(qf[0][0], k0[2], s[j], 0, 0, 0);
      s[j] = __builtin_amdgcn_mfma_f32_16x16x32_bf16(qf[0][1], k1[2], s[j], 0, 0, 0);
      s[j] = __builtin_amdgcn_mfma_f32_16x16x32_bf16(qf[1][0], k0[1], s[j], 0, 0, 0);
      s[j] = __builtin_amdgcn_mfma_f32_16x16x32_bf16(qf[1][1], k1[1], s[j], 0, 0, 0);
      s[j] = __builtin_amdgcn_mfma_f32_16x16x32_bf16(qf[2][0], k0[0], s[j], 0, 0, 0);
      s[j] = __builtin_amdgcn_mfma_f32_16x16x32_bf16(qf[2][1], k1[0], s[j], 0, 0, 0);
    }

    const bool diag = (kt == qt);
#pragma unroll
    for (int rr = 0; rr < 4; rr++) {
      const int q = q0 + 4 * lg + rr;
      float mx = -1e30f;
#pragma unroll
      for (int j = 0; j < 4; j++) {
        float v = s[j][rr] * 0.125f;
        if (diag && (kb + 16 * j + lr > q)) v = -1e30f;
        s[j][rr] = v;
        mx = fmaxf(mx, v);
      }
      mx = fmaxf(mx, __shfl_xor(mx, 1));
      mx = fmaxf(mx, __shfl_xor(mx, 2));
      mx = fmaxf(mx, __shfl_xor(mx, 4));
      mx = fmaxf(mx, __shfl_xor(mx, 8));
      float mn = fmaxf(m[rr], mx);
      float al = expf(m[rr] - mn);
      m[rr] = mn;
      l[rr] *= al;
#pragma unroll
      for (int j = 0; j < 4; j++) Y[j][rr] *= al;
      float ps = 0.f;
#pragma unroll
      for (int j = 0; j < 4; j++) {
        float p = expf(s[j][rr] - mn);
        s[j][rr] = p;
        ps += p;
      }
      l[rr] += ps;
    }

#pragma unroll
    for (int j = 0; j < 4; j++) {
      const int jh = j >> 1;
      const int col = 16 * (j & 1) + lr;
#pragma unroll
      for (int rr = 0; rr < 4; rr++) {
        float p = s[j][rr];
        unsigned short w0 = f2bf(p);
        float r = p - bf2f(w0);
        unsigned short w1 = f2bf(r);
        r -= bf2f(w1);
        const int o = (4 * lg + rr) * 32 + col;
        sP[0][jh][wv][o] = w0;
        sP[1][jh][wv][o] = w1;
        sP[2][jh][wv][o] = f2bf(r);
      }
    }
    __syncthreads();
    const int po = lr * 32 + 8 * lg;
    short8 pf[3][2];
#pragma unroll
    for (int lv = 0; lv < 3; lv++) {
      pf[lv][0] = *(const short8*)(&sP[lv][0][wv][po]);
      pf[lv][1] = *(const short8*)(&sP[lv][1][wv][po]);
    }
#pragma unroll
    for (int jd = 0; jd < 4; jd++) {
      const int vo = (16 * jd + lr) * 32 + 8 * lg;
      short8 v0[3], v1[3];
#pragma unroll
      for (int lv = 0; lv < 3; lv++) {
        v0[lv] = *(const short8*)(&sV[lv][0][vo]);
        v1[lv] = *(const short8*)(&sV[lv][1][vo]);
      }
      Y[jd] = __builtin_amdgcn_mfma_f32_16x16x32_bf16(pf[0][0], v0[0], Y[jd], 0, 0, 0);
      Y[jd] = __builtin_amdgcn_mfma_f32_16x16x32_bf16(pf[0][1], v1[0], Y[jd], 0, 0, 0);
      Y[jd] = __builtin_amdgcn_mfma_f32_16x16x32_bf16(pf[0][0], v0[1], Y[jd], 0, 0, 0);
      Y[jd] = __builtin_amdgcn_mfma_f32_16x16x32_bf16(pf[0][1], v1[1], Y[jd], 0, 0, 0);
      Y[jd] = __builtin_amdgcn_mfma_f32_16x16x32_bf16(pf[1][0], v0[0], Y[jd], 0, 0, 0);
      Y[jd] = __builtin_amdgcn_mfma_f32_16x16x32_bf16(pf[1][1], v1[0], Y[jd], 0, 0, 0);
      Y[jd] = __builtin_amdgcn_mfma_f32_16x16x32_bf16(pf[0][0], v0[2], Y[jd], 0, 0, 0);
      Y[jd] = __builtin_amdgcn_mfma_f32_16x16x32_bf16(pf[0][1], v1[2], Y[jd], 0, 0, 0);
      Y[jd] = __builtin_amdgcn_mfma_f32_16x16x32_bf16(pf[1][0], v0[1], Y[jd], 0, 0, 0);
      Y[jd] = __builtin_amdgcn_mfma_f32_16x16x32_bf16(pf[1][1], v1[1], Y[jd], 0, 0, 0);
      Y[jd] = __builtin_amdgcn_mfma_f32_16x16x32_bf16(pf[2][0], v0[0], Y[jd], 0, 0, 0);
      Y[jd] = __builtin_amdgcn_mfma_f32_16x16x32_bf16(pf[2][1], v1[0], Y[jd], 0, 0, 0);
    }
  }

#pragma unroll
  for (int rr = 0; rr < 4; rr++) {
    float t = l[rr];
    t += __shfl_xor(t, 1); t += __shfl_xor(t, 2);
    t += __shfl_xor(t, 4); t += __shfl_xor(t, 8);
    l[rr] = 1.0f / t;
  }
#pragma unroll
  for (int jd = 0; jd < 4; jd++) {
    const int d = 16 * jd + lr;
#pragma unroll
    for (int rr = 0; rr < 4; rr++) {
      const int q = q0 + 4 * lg + rr;
      float v = Y[jd][rr] * l[rr];
      unsigned short w0 = f2bf(v);
      const size_t ci = ((size_t)(b * TSEQ + q)) * CDIM + h * DHEAD + d;
      ath[ci] = w0;
      atl[ci] = f2bf(v - bf2f(w0));
    }
  }
}

// ---------------- LayerNorm f32 -> split hi/lo bf16 (R8 proven) ----------------
__global__ __launch_bounds__(256) void ln_split_kernel(const float* __restrict__ x,
                                                       unsigned short* __restrict__ yh,
                                                       unsigned short* __restrict__ yl,
                                                       const float* __restrict__ g,
                                                       const float* __restrict__ b) {
  int n = blockIdx.x, tid = threadIdx.x;
  const float4* xr = (const float4*)(x + (size_t)n * CDIM);
  float4 v = xr[tid];
  float s = v.x + v.y + v.z + v.w;
  float ss = v.x * v.x + v.y * v.y + v.z * v.z + v.w * v.w;
  __shared__ float rs[256], rss[256];
  rs[tid] = s; rss[tid] = ss;
  __syncthreads();
  for (int o = 128; o > 0; o >>= 1) {
    if (tid < o) { rs[tid] += rs[tid + o]; rss[tid] += rss[tid + o]; }
    __syncthreads();
  }
  float m = rs[0] * (1.0f / CDIM);
  float var = rss[0] * (1.0f / CDIM) - m * m;
  float r = rsqrtf(var + 1e-5f);
  float4 gv = ((const float4*)g)[tid];
  float4 bv = ((const float4*)b)[tid];
  float o0 = (v.x - m) * r * gv.x + bv.x;
  float o1 = (v.y - m) * r * gv.y + bv.y;
  float o2 = (v.z - m) * r * gv.z + bv.z;
  float o3 = (v.w - m) * r * gv.w + bv.w;
  ushort4 hh, ll;
  hh.x = f2bf(o0); ll.x = f2bf(o0 - bf2f(hh.x));
  hh.y = f2bf(o1); ll.y = f2bf(o1 - bf2f(hh.y));
  hh.z = f2bf(o2); ll.z = f2bf(o2 - bf2f(hh.z));
  hh.w = f2bf(o3); ll.w = f2bf(o3 - bf2f(hh.w));
  ((ushort4*)(yh + (size_t)n * CDIM))[tid] = hh;
  ((ushort4*)(yl + (size_t)n * CDIM))[tid] = ll;
}

// ---------------- f32 -> bf16 convert (R7 proven) ----------------
__global__ __launch_bounds__(256) void cvt_bf16_kernel(const float* __restrict__ x,
                                                       unsigned short* __restrict__ y) {
  int i = blockIdx.x * 256 + threadIdx.x;
  float4 v = ((const float4*)x)[i];
  ushort4 o;
  o.x = f2bf(v.x); o.y = f2bf(v.y); o.z = f2bf(v.z); o.w = f2bf(v.w);
  ((ushort4*)y)[i] = o;
}

// ---------------- LayerNorm f32 -> bf16 (R4 proven) ----------------
__global__ __launch_bounds__(256) void ln_bf16_kernel(const float* __restrict__ x,
                                                      unsigned short* __restrict__ y,
                                                      const float* __restrict__ g,
                                                      const float* __restrict__ b) {
  int n = blockIdx.x, tid = threadIdx.x;
  const float4* xr = (const float4*)(x + (size_t)n * CDIM);
  float4 v = xr[tid];
  float s = v.x + v.y + v.z + v.w;
  float ss = v.x * v.x + v.y * v.y + v.z * v.z + v.w * v.w;
  __shared__ float rs[256], rss[256];
  rs[tid] = s; rss[tid] = ss;
  __syncthreads();
  for (int o = 128; o > 0; o >>= 1) {
    if (tid < o) { rs[tid] += rs[tid + o]; rss[tid] += rss[tid + o]; }
    __syncthreads();
  }
  float m = rs[0] * (1.0f / CDIM);
  float var = rss[0] * (1.0f / CDIM) - m * m;
  float r = rsqrtf(var + 1e-5f);
  float4 gv = ((const float4*)g)[tid];
  float4 bv = ((const float4*)b)[tid];
  ushort4 o4;
  o4.x = f2bf((v.x - m) * r * gv.x + bv.x);
  o4.y = f2bf((v.y - m) * r * gv.y + bv.y);
  o4.z = f2bf((v.z - m) * r * gv.z + bv.z);
  o4.w = f2bf((v.w - m) * r * gv.w + bv.w);
  ((ushort4*)(y + (size_t)n * CDIM))[tid] = o4;
}

// ---------------- weight transpose+convert bf16, z-batched (R4 core) ----------------
__global__ __launch_bounds__(256) void wconv_t_kernel(const float* __restrict__ W,
                                                      unsigned short* __restrict__ Wt,
                                                      int K, int N,
                                                      size_t wstride, size_t ostride) {
  __shared__ float t[32][33];
  W  += (size_t)blockIdx.z * wstride;
  Wt += (size_t)blockIdx.z * ostride;
  int n0 = blockIdx.x * 32, k0 = blockIdx.y * 32;
  int tx = threadIdx.x & 31, ty = threadIdx.x >> 5;
#pragma unroll
  for (int i = 0; i < 4; i++)
    t[ty + 8 * i][tx] = W[(size_t)(k0 + ty + 8 * i) * N + n0 + tx];
  __syncthreads();
#pragma unroll
  for (int i = 0; i < 4; i++)
    Wt[(size_t)(n0 + ty + 8 * i) * K + k0 + tx] = f2bf(t[tx][ty + 8 * i]);
}

// ---------------- weight transpose + hi/lo split (R8 proven) ----------------
__global__ __launch_bounds__(256) void wconv_split_kernel(const float* __restrict__ W,
                                                          unsigned short* __restrict__ Wh,
                                                          unsigned short* __restrict__ Wl,
                                                          int K, int N) {
  __shared__ float t[32][33];
  int n0 = blockIdx.x * 32, k0 = blockIdx.y * 32;
  int tx = threadIdx.x & 31, ty = threadIdx.x >> 5;
#pragma unroll
  for (int i = 0; i < 4; i++)
    t[ty + 8 * i][tx] = W[(size_t)(k0 + ty + 8 * i) * N + n0 + tx];
  __syncthreads();
#pragma unroll
  for (int i = 0; i < 4; i++) {
    float w = t[tx][ty + 8 * i];
    unsigned short h = f2bf(w);
    size_t o = (size_t)(n0 + ty + 8 * i) * K + k0 + tx;
    Wh[o] = h;
    Wl[o] = f2bf(w - bf2f(h));
  }
}

// XCD-chunked bijective swizzle (requires gridDim.x*gridDim.y % 8 == 0)
__device__ __forceinline__ void xcd_swz(int& bx, int& by) {
  int bid = blockIdx.y * gridDim.x + blockIdx.x;
  int cpx = (gridDim.x * gridDim.y) >> 3;
  bid = (bid & 7) * cpx + (bid >> 3);
  bx = bid % gridDim.x;
  by = bid / gridDim.x;
}

// ---------------- split-bf16 MFMA GEMM (R8 core) + fused epilogues (R14 proven) ----------------
// MODE 0: C=v   1: gelu(v+bias) -> split Ch,Cl   2: C+=v   3: C+=v+bias
template <int MODE>
__global__ __launch_bounds__(256) void gemm_split(const unsigned short* __restrict__ Ah,
                                                  const unsigned short* __restrict__ Al,
                                                  const unsigned short* __restrict__ Bth,
                                                  const unsigned short* __restrict__ Btl,
                                                  float* __restrict__ C,
                                                  unsigned short* __restrict__ Ch,
                                                  unsigned short* __restrict__ Cl,
                                                  const float* __restrict__ bias,
                                                  int M, int Nn, int K) {
  __shared__ __align__(16) unsigned short AsH[128 * 32];
  __shared__ __align__(16) unsigned short AsL[128 * 32];
  __shared__ __align__(16) unsigned short BsH[128 * 32];
  __shared__ __align__(16) unsigned short BsL[128 * 32];
  const int tid = threadIdx.x;
  const int wv = tid >> 6, ln = tid & 63;
  int sbx, sby;
  xcd_swz(sbx, sby);
  const int bm = sby * 128, bn = sbx * 128;

  const size_t aoff0 = (size_t)(bm + 32 * wv + (ln >> 2)) * K + (size_t)((ln & 3) * 8);
  const size_t aoff1 = aoff0 + (size_t)16 * K;
  const size_t boff0 = (size_t)(bn + 32 * wv + (ln >> 2)) * K + (size_t)((ln & 3) * 8);
  const size_t boff1 = boff0 + (size_t)16 * K;
  const int lofs = 1024 * wv + ln * 8;

  const int wm = wv >> 1, wn = wv & 1;
  const int lr = ln & 15, lg = ln >> 4;

  f32x4 acc[4][4];
#pragma unroll
  for (int i = 0; i < 4; i++)
#pragma unroll
    for (int j = 0; j < 4; j++) acc[i][j] = (f32x4){0.f, 0.f, 0.f, 0.f};

  for (int k0 = 0; k0 < K; k0 += 32) {
    short8 rah0 = *(const short8*)(Ah + aoff0 + k0);
    short8 rah1 = *(const short8*)(Ah + aoff1 + k0);
    short8 ral0 = *(const short8*)(Al + aoff0 + k0);
    short8 ral1 = *(const short8*)(Al + aoff1 + k0);
    short8 rbh0 = *(const short8*)(Bth + boff0 + k0);
    short8 rbh1 = *(const short8*)(Bth + boff1 + k0);
    short8 rbl0 = *(const short8*)(Btl + boff0 + k0);
    short8 rbl1 = *(const short8*)(Btl + boff1 + k0);
    __syncthreads();
    *(short8*)(AsH + lofs)       = rah0;
    *(short8*)(AsH + lofs + 512) = rah1;
    *(short8*)(AsL + lofs)       = ral0;
    *(short8*)(AsL + lofs + 512) = ral1;
    *(short8*)(BsH + lofs)       = rbh0;
    *(short8*)(BsH + lofs + 512) = rbh1;
    *(short8*)(BsL + lofs)       = rbl0;
    *(short8*)(BsL + lofs + 512) = rbl1;
    __syncthreads();

    short8 afh[4], afl[4], bwh[4], bwl[4];
#pragma unroll
    for (int i = 0; i < 4; i++) {
      const int ao = (64 * wm + 16 * i + lr) * 32 + 8 * lg;
      afh[i] = *(const short8*)(AsH + ao);
      afl[i] = *(const short8*)(AsL + ao);
    }
#pragma unroll
    for (int j = 0; j < 4; j++) {
      const int bo = (64 * wn + 16 * j + lr) * 32 + 8 * lg;
      bwh[j] = *(const short8*)(BsH + bo);
      bwl[j] = *(const short8*)(BsL + bo);
    }
#pragma unroll
    for (int i = 0; i < 4; i++)
#pragma unroll
      for (int j = 0; j < 4; j++) {
        acc[i][j] = __builtin_amdgcn_mfma_f32_16x16x32_bf16(afh[i], bwh[j], acc[i][j], 0, 0, 0);
        acc[i][j] = __builtin_amdgcn_mfma_f32_16x16x32_bf16(afl[i], bwh[j], acc[i][j], 0, 0, 0);
        acc[i][j] = __builtin_amdgcn_mfma_f32_16x16x32_bf16(afh[i], bwl[j], acc[i][j], 0, 0, 0);
      }
  }

#pragma unroll
  for (int j = 0; j < 4; j++) {
    const int n = bn + 64 * wn + 16 * j + lr;
    const float bb = (MODE == 1 || MODE == 3) ? bias[n] : 0.0f;
#pragma unroll
    for (int i = 0; i < 4; i++) {
#pragma unroll
      for (int rr = 0; rr < 4; rr++) {
        const int m = bm + 64 * wm + 16 * i + 4 * lg + rr;
        float v = acc[i][j][rr];
        const size_t ci = (size_t)m * Nn + n;
        if constexpr (MODE == 0) {
          C[ci] = v;
        } else if constexpr (MODE == 1) {
          v += bb;
          v = 0.5f * v * (1.0f + erff(v * 0.70710678118654752f));
          unsigned short h = f2bf(v);
          Ch[ci] = h;
          Cl[ci] = f2bf(v - bf2f(h));
        } else if constexpr (MODE == 2) {
          C[ci] += v;
        } else {
          C[ci] += v + bb;
        }
      }
    }
  }
}

// ---------------- bf16 MFMA GEMM (R4/R7 core), head ----------------
__global__ __launch_bounds__(256) void gemm_bf16(const unsigned short* __restrict__ A,
                                                 const unsigned short* __restrict__ Bt,
                                                 float* __restrict__ C,
                                                 int M, int Nn, int K) {
  __shared__ __align__(16) unsigned short As[128 * 32];
  __shared__ __align__(16) unsigned short Bs[128 * 32];
  const int tid = threadIdx.x;
  const int wv = tid >> 6, ln = tid & 63;
  int sbx, sby;
  xcd_swz(sbx, sby);
  const int bm = sby * 128, bn = sbx * 128;

  const size_t aoff0 = (size_t)(bm + 32 * wv + (ln >> 2)) * K + (size_t)((ln & 3) * 8);
  const size_t aoff1 = aoff0 + (size_t)16 * K;
  const size_t boff0 = (size_t)(bn + 32 * wv + (ln >> 2)) * K + (size_t)((ln & 3) * 8);
  const size_t boff1 = boff0 + (size_t)16 * K;
  const int lofs = 1024 * wv + ln * 8;

  const int wm = wv >> 1, wn = wv & 1;
  const int lr = ln & 15, lg = ln >> 4;

  f32x4 acc[4][4];
#pragma unroll
  for (int i = 0; i < 4; i++)
#pragma unroll
    for (int j = 0; j < 4; j++) acc[i][j] = (f32x4){0.f, 0.f, 0.f, 0.f};

  for (int k0 = 0; k0 < K; k0 += 32) {
    short8 ra0 = *(const short8*)(A + aoff0 + k0);
    short8 ra1 = *(const short8*)(A + aoff1 + k0);
    short8 rb0 = *(const short8*)(Bt + boff0 + k0);
    short8 rb1 = *(const short8*)(Bt + boff1 + k0);
    __syncthreads();
    *(short8*)(As + lofs)       = ra0;
    *(short8*)(As + lofs + 512) = ra1;
    *(short8*)(Bs + lofs)       = rb0;
    *(short8*)(Bs + lofs + 512) = rb1;
    __syncthreads();

    short8 af[4], bw[4];
#pragma unroll
    for (int i = 0; i < 4; i++)
      af[i] = *(const short8*)(As + ((64 * wm + 16 * i + lr) * 32 + 8 * lg));
#pragma unroll
    for (int j = 0; j < 4; j++)
      bw[j] = *(const short8*)(Bs + ((64 * wn + 16 * j + lr) * 32 + 8 * lg));
#pragma unroll
    for (int i = 0; i < 4; i++)
#pragma unroll
      for (int j = 0; j < 4; j++)
        acc[i][j] = __builtin_amdgcn_mfma_f32_16x16x32_bf16(af[i], bw[j], acc[i][j], 0, 0, 0);
  }

#pragma unroll
  for (int j = 0; j < 4; j++) {
    const int n = bn + 64 * wn + 16 * j + lr;
#pragma unroll
    for (int i = 0; i < 4; i++) {
#pragma unroll
      for (int r = 0; r < 4; r++) {
        const int m = bm + 64 * wm + 16 * i + 4 * lg + r;
        C[(size_t)m * Nn + n] = acc[i][j][r];
      }
    }
  }
}

// ---------------- batched sparse MoE GEMM 1 (z = expert): gather-A, gelu out ----------------
__global__ __launch_bounds__(256) void gemm_moe1(const unsigned short* __restrict__ A,
                                                 const unsigned short* __restrict__ BtAll,
                                                 unsigned short* __restrict__ CuAll,
                                                 const float* __restrict__ biasAll,
                                                 const int* __restrict__ cntAll,
                                                 const int* __restrict__ lstAll,
                                                 int Nn, int K) {
  const int e = blockIdx.z;
  const int ce = cntAll[e];
  const int bm = blockIdx.y * 128, bn = blockIdx.x * 128;
  if (bm >= ce) return;
  const unsigned short* Bt = BtAll + (size_t)e * Nn * K;
  unsigned short* Cu = CuAll + (size_t)e * NTOK * Nn;
  const float* bias = biasAll + (size_t)e * Nn;
  const int* lst = lstAll + (size_t)e * NTOK;

  __shared__ __align__(16) unsigned short As[128 * 32];
  __shared__ __align__(16) unsigned short Bs[128 * 32];
  const int tid = threadIdx.x;
  const int wv = tid >> 6, ln = tid & 63;

  const int ra = bm + 32 * wv + (ln >> 2);
  const int t0 = lst[(ra      < ce) ? ra      : 0];
  const int t1 = lst[(ra + 16 < ce) ? ra + 16 : 0];
  const size_t aoff0 = (size_t)t0 * K + (size_t)((ln & 3) * 8);
  const size_t aoff1 = (size_t)t1 * K + (size_t)((ln & 3) * 8);
  const size_t boff0 = (size_t)(bn + 32 * wv + (ln >> 2)) * K + (size_t)((ln & 3) * 8);
  const size_t boff1 = boff0 + (size_t)16 * K;
  const int lofs = 1024 * wv + ln * 8;

  const int wm = wv >> 1, wn = wv & 1;
  const int lr = ln & 15, lg = ln >> 4;

  f32x4 acc[4][4];
#pragma unroll
  for (int i = 0; i < 4; i++)
#pragma unroll
    for (int j = 0; j < 4; j++) acc[i][j] = (f32x4){0.f, 0.f, 0.f, 0.f};

  for (int k0 = 0; k0 < K; k0 += 32) {
    short8 ra0 = *(const short8*)(A + aoff0 + k0);
    short8 ra1 = *(const short8*)(A + aoff1 + k0);
    short8 rb0 = *(const short8*)(Bt + boff0 + k0);
    short8 rb1 = *(const short8*)(Bt + boff1 + k0);
    __syncthreads();
    *(short8*)(As + lofs)       = ra0;
    *(short8*)(As + lofs + 512) = ra1;
    *(short8*)(Bs + lofs)       = rb0;
    *(short8*)(Bs + lofs + 512) = rb1;
    __syncthreads();

    short8 af[4], bw[4];
#pragma unroll
    for (int i = 0; i < 4; i++)
      af[i] = *(const short8*)(As + ((64 * wm + 16 * i + lr) * 32 + 8 * lg));
#pragma unroll
    for (int j = 0; j < 4; j++)
      bw[j] = *(const short8*)(Bs + ((64 * wn + 16 * j + lr) * 32 + 8 * lg));
#pragma unroll
    for (int i = 0; i < 4; i++)
#pragma unroll
      for (int j = 0; j < 4; j++)
        acc[i][j] = __builtin_amdgcn_mfma_f32_16x16x32_bf16(af[i], bw[j], acc[i][j], 0, 0, 0);
  }

#pragma unroll
  for (int j = 0; j < 4; j++) {
    const int n = bn + 64 * wn + 16 * j + lr;
    const float bb = bias[n];
#pragma unroll
    for (int i = 0; i < 4; i++) {
#pragma unroll
      for (int r = 0; r < 4; r++) {
        const int m = bm + 64 * wm + 16 * i + 4 * lg + r;
        float v = acc[i][j][r] + bb;
        v = 0.5f * v * (1.0f + erff(v * 0.70710678118654752f));
        Cu[(size_t)m * Nn + n] = f2bf(v);
      }
    }
  }
}

// ---------------- batched sparse MoE GEMM 2 (z = expert): atomic scatter out ----------------
__global__ __launch_bounds__(256) void gemm_moe2(const unsigned short* __restrict__ AAll,
                                                 const unsigned short* __restrict__ BtAll,
                                                 float* __restrict__ C,
                                                 const float* __restrict__ biasAll,
                                                 const int* __restrict__ cntAll,
                                                 const int* __restrict__ lstAll,
                                                 const float* __restrict__ wtsAll,
                                                 int Nn, int K) {
  const int e = blockIdx.z;
  const int ce = cntAll[e];
  const int bm = blockIdx.y * 128, bn = blockIdx.x * 128;
  if (bm >= ce) return;
  const unsigned short* A = AAll + (size_t)e * NTOK * K;
  const unsigned short* Bt = BtAll + (size_t)e * Nn * K;
  const float* bias = biasAll + (size_t)e * Nn;
  const int* lst = lstAll + (size_t)e * NTOK;
  const float* wts = wtsAll + (size_t)e * NTOK;

  __shared__ __align__(16) unsigned short As[128 * 32];
  __shared__ __align__(16) unsigned short Bs[128 * 32];
  const int tid = threadIdx.x;
  const int wv = tid >> 6, ln = tid & 63;

  const size_t aoff0 = (size_t)(bm + 32 * wv + (ln >> 2)) * K + (size_t)((ln & 3) * 8);
  const size_t aoff1 = aoff0 + (size_t)16 * K;
  const size_t boff0 = (size_t)(bn + 32 * wv + (ln >> 2)) * K + (size_t)((ln & 3) * 8);
  const size_t boff1 = boff0 + (size_t)16 * K;
  const int lofs = 1024 * wv + ln * 8;

  const int wm = wv >> 1, wn = wv & 1;
  const int lr = ln & 15, lg = ln >> 4;

  f32x4 acc[4][4];
#pragma unroll
  for (int i = 0; i < 4; i++)
#pragma unroll
    for (int j = 0; j < 4; j++) acc[i][j] = (f32x4){0.f, 0.f, 0.f, 0.f};

  for (int k0 = 0; k0 < K; k0 += 32) {
    short8 ra0 = *(const short8*)(A + aoff0 + k0);
    short8 ra1 = *(const short8*)(A + aoff1 + k0);
    short8 rb0 = *(const short8*)(Bt + boff0 + k0);
    short8 rb1 = *(const short8*)(Bt + boff1 + k0);
    __syncthreads();
    *(short8*)(As + lofs)       = ra0;
    *(short8*)(As + lofs + 512) = ra1;
    *(short8*)(Bs + lofs)       = rb0;
    *(short8*)(Bs + lofs + 512) = rb1;
    __syncthreads();

    short8 af[4], bw[4];
#pragma unroll
    for (int i = 0; i < 4; i++)
      af[i] = *(const short8*)(As + ((64 * wm + 16 * i + lr) * 32 + 8 * lg));
#pragma unroll
    for (int j = 0; j < 4; j++)
      bw[j] = *(const short8*)(Bs + ((64 * wn + 16 * j + lr) * 32 + 8 * lg));
#pragma unroll
    for (int i = 0; i < 4; i++)
#pragma unroll
      for (int j = 0; j < 4; j++)
        acc[i][j] = __builtin_amdgcn_mfma_f32_16x16x32_bf16(af[i], bw[j], acc[i][j], 0, 0, 0);
  }

#pragma unroll
  for (int j = 0; j < 4; j++) {
    const int n = bn + 64 * wn + 16 * j + lr;
    const float bb = bias[n];
#pragma unroll
    for (int i = 0; i < 4; i++) {
#pragma unroll
      for (int r = 0; r < 4; r++) {
        const int m = bm + 64 * wm + 16 * i + 4 * lg + r;
        if (m < ce) {
          const int tok = lst[m];
          atomicAdd(&C[(size_t)tok * Nn + n], wts[m] * (acc[i][j][r] + bb));
        }
      }
    }
  }
}

// ---------------- router -> per-expert token lists (R15 proven) ----------------
__global__ __launch_bounds__(64) void router2_kernel(const float* __restrict__ x,
                                                     const float* __restrict__ rw,
                                                     int* __restrict__ cnt,
                                                     int* __restrict__ lst,
                                                     float* __restrict__ wts) {
  int n = blockIdx.x, lane = threadIdx.x;
  const float* xr = x + (size_t)n * CDIM;
  float acc[NEXP] = {};
  for (int i = 0; i < CDIM / 64; i++) {
    int c = lane + 64 * i;
    float xv = xr[c];
    const float* r = rw + (size_t)c * NEXP;
#pragma unroll
    for (int e = 0; e < NEXP; e++) acc[e] += xv * r[e];
  }
  for (int m = 32; m >= 1; m >>= 1)
#pragma unroll
    for (int e = 0; e < NEXP; e++) acc[e] += __shfl_xor(acc[e], m);
  if (lane == 0) {
    float mx = acc[0];
#pragma unroll
    for (int e = 1; e < NEXP; e++) mx = fmaxf(mx, acc[e]);
    float p[NEXP];
#pragma unroll
    for (int e = 0; e < NEXP; e++) p[e] = expf(acc[e] - mx);
    int i1 = 0;
#pragma unroll
    for (int e = 1; e < NEXP; e++) if (p[e] > p[i1]) i1 = e;
    int i2 = (i1 == 0) ? 1 : 0;
#pragma unroll
    for (int e = 0; e < NEXP; e++) if (e != i1 && p[e] > p[i2]) i2 = e;
    float denom = p[i1] + p[i2];
    int p1 = atomicAdd(&cnt[i1], 1);
    lst[i1 * NTOK + p1] = n;
    wts[i1 * NTOK + p1] = p[i1] / denom;
    int p2 = atomicAdd(&cnt[i2], 1);
    lst[i2 * NTOK + p2] = n;
    wts[i2 * NTOK + p2] = p[i2] / denom;
  }
}

extern "C" void kernel_launch(void* const* d_in, const int* in_sizes, int n_in,
                              void* d_out, int out_size, void* d_ws, size_t ws_size,
                              hipStream_t stream) {
  const int*   idx      = (const int*)d_in[0];
  const float* tok_emb  = (const float*)d_in[1];
  const float* ln1_g    = (const float*)d_in[2];
  const float* ln1_b    = (const float*)d_in[3];
  const float* ln2_g    = (const float*)d_in[4];
  const float* ln2_b    = (const float*)d_in[5];
  const float* qkv_w    = (const float*)d_in[6];
  const float* proj_w   = (const float*)d_in[7];
  const float* ff_w1    = (const float*)d_in[8];
  const float* ff_b1    = (const float*)d_in[9];
  const float* ff_w2    = (const float*)d_in[10];
  const float* ff_b2    = (const float*)d_in[11];
  const float* router_w = (const float*)d_in[12];
  const float* exp_w1   = (const float*)d_in[13];
  const float* exp_b1   = (const float*)d_in[14];
  const float* exp_w2   = (const float*)d_in[15];
  const float* exp_b2   = (const float*)d_in[16];
  const float* lnf_g    = (const float*)d_in[17];
  const float* lnf_b    = (const float*)d_in[18];
  const float* head_w   = (const float*)d_in[19];
  float* out = (float*)d_out;

  // ---- workspace layout (~144 MB) ----
  const size_t NC = (size_t)NTOK * CDIM;
  char* w = (char*)d_ws;
  float* x  = (float*)w;                 w += NC * 4;
  unsigned short* S1 = (unsigned short*)w; w += NC * 4;
  float* Q  = (float*)w;                 w += (size_t)NTOK * C3 * 4;
  float* C3r = (float*)w;                w += NC * 4;
  unsigned short* WS = (unsigned short*)w; w += NC * 4;
  unsigned short* EX = (unsigned short*)w; w += NC * 6;
  float* ct = (float*)w;                 w += (size_t)TSEQ * 32 * 4;
  float* st = (float*)w;                 w += (size_t)TSEQ * 32 * 4;
  int*   moe_cnt = (int*)w;              w += NEXP * 4;
  int*   moe_lst = (int*)w;              w += (size_t)NEXP * NTOK * 4;
  float* moe_wts = (float*)w;            w += (size_t)NEXP * NTOK * 4;

  // trunk aliases
  unsigned short* xh = S1;
  unsigned short* xl = S1 + NC;
  unsigned short* Wh = WS;
  unsigned short* Wl = WS + NC;
  float* qkvf = Q;
  // attention-phase aliases
  unsigned short* Qh_s = S1;
  unsigned short* Qm_s = S1 + NC;
  unsigned short* Ql_s = EX;
  unsigned short* Kh_s = (unsigned short*)C3r;
  unsigned short* Km_s = (unsigned short*)C3r + NC;
  unsigned short* Kl_s = EX + NC;
  unsigned short* Vth_s = WS;
  unsigned short* Vtm_s = WS + NC;
  unsigned short* Vtl_s = EX + 2 * NC;
  unsigned short* ath = (unsigned short*)Q;
  unsigned short* atl = (unsigned short*)Q + NC;
  // FF aliases
  unsigned short* hh = (unsigned short*)Q;
  unsigned short* hl = (unsigned short*)Q + (size_t)NTOK * FFDIM;
  // MoE aliases (batched)
  unsigned short* x_bf   = S1;
  unsigned short* exp1t  = EX;
  unsigned short* exp2t  = WS;
  unsigned short* hmoeC  = (unsigned short*)Q;      // [NEXP][NTOK][DEXP] bf16, 64MB
  float* moe_out  = x;
  // head aliases
  unsigned short* xn_bf   = S1;
  unsigned short* wt_head = (unsigned short*)Q;

  embed_kernel<<<NTOK, 256, 0, stream>>>(idx, tok_emb, x);
  rope_table_kernel<<<TSEQ, 32, 0, stream>>>(ct, st);

  for (int l = 0; l < LAYERS; l++) {
    // --- attention sublayer ---
    ln_split_kernel<<<NTOK, 256, 0, stream>>>(x, xh, xl, ln1_g + l * CDIM, ln1_b + l * CDIM);
    wconv_split_kernel<<<dim3(C3 / 32, CDIM / 32), 256, 0, stream>>>(
        qkv_w + (size_t)l * CDIM * C3, Wh, Wl, CDIM, C3);
    gemm_split<0><<<dim3(C3 / 128, NTOK / 128), 256, 0, stream>>>(
        xh, xl, Wh, Wl, qkvf, nullptr, nullptr, nullptr, NTOK, C3, CDIM);
    qkv_prep_kernel<<<dim3(TSEQ / 64, HEADS, 8), 256, 0, stream>>>(
        qkvf, ct, st, Qh_s, Qm_s, Ql_s, Kh_s, Km_s, Kl_s, Vth_s, Vtm_s, Vtl_s);
    flash_attn_kernel<<<dim3(TSEQ / 64, HEADS, 8), 256, 0, stream>>>(
        Qh_s, Qm_s, Ql_s, Kh_s, Km_s, Kl_s, Vth_s, Vtm_s, Vtl_s, ath, atl);
    wconv_split_kernel<<<dim3(CDIM / 32, CDIM / 32), 256, 0, stream>>>(
        proj_w + (size_t)l * CDIM * CDIM, Wh, Wl, CDIM, CDIM);
    gemm_split<2><<<dim3(CDIM / 128, NTOK / 128), 256, 0, stream>>>(
        ath, atl, Wh, Wl, x, nullptr, nullptr, nullptr, NTOK, CDIM, CDIM);
    // --- FF sublayer ---
    ln_split_kernel<<<NTOK, 256, 0, stream>>>(x, xh, xl, ln2_g + l * CDIM, ln2_b + l * CDIM);
    wconv_split_kernel<<<dim3(FFDIM / 32, CDIM / 32), 256, 0, stream>>>(
        ff_w1 + (size_t)l * CDIM * FFDIM, Wh, Wl, CDIM, FFDIM);
    gemm_split<1><<<dim3(FFDIM / 128, NTOK / 128), 256, 0, stream>>>(
        xh, xl, Wh, Wl, nullptr, hh, hl, ff_b1 + (size_t)l * FFDIM, NTOK, FFDIM, CDIM);
    wconv_split_kernel<<<dim3(CDIM / 32, FFDIM / 32), 256, 0, stream>>>(
        ff_w2 + (size_t)l * FFDIM * CDIM, Wh, Wl, FFDIM, CDIM);
    gemm_split<3><<<dim3(CDIM / 128, NTOK / 128), 256, 0, stream>>>(
        hh, hl, Wh, Wl, x, nullptr, nullptr, ff_b2 + (size_t)l * CDIM, NTOK, CDIM, FFDIM);
  }

  // --- batched sparse top-2 MoE ---
  hipMemsetAsync(moe_cnt, 0, NEXP * sizeof(int), stream);
  router2_kernel<<<NTOK, 64, 0, stream>>>(x, router_w, moe_cnt, moe_lst, moe_wts);
  cvt_bf16_kernel<<<(NC / 4) / 256, 256, 0, stream>>>(x, x_bf);
  wconv_t_kernel<<<dim3(DEXP / 32, CDIM / 32, NEXP), 256, 0, stream>>>(
      exp_w1, exp1t, CDIM, DEXP, (size_t)CDIM * DEXP, (size_t)CDIM * DEXP);
  wconv_t_kernel<<<dim3(CDIM / 32, DEXP / 32, NEXP), 256, 0, stream>>>(
      exp_w2, exp2t, DEXP, CDIM, (size_t)DEXP * CDIM, (size_t)DEXP * CDIM);
  gemm_moe1<<<dim3(DEXP / 128, NTOK / 128, NEXP), 256, 0, stream>>>(
      x_bf, exp1t, hmoeC, exp_b1, moe_cnt, moe_lst, DEXP, CDIM);
  hipMemsetAsync(moe_out, 0, NC * sizeof(float), stream);
  gemm_moe2<<<dim3(CDIM / 128, NTOK / 128, NEXP), 256, 0, stream>>>(
      hmoeC, exp2t, moe_out, exp_b2, moe_cnt, moe_lst, moe_wts, CDIM, DEXP);

  // --- head ---
  ln_bf16_kernel<<<NTOK, 256, 0, stream>>>(moe_out, xn_bf, lnf_g, lnf_b);
  wconv_t_kernel<<<dim3(VOCAB / 32, CDIM / 32, 1), 256, 0, stream>>>(
      head_w, wt_head, CDIM, VOCAB, 0, 0);
  gemm_bf16<<<dim3(VOCAB / 128, NTOK / 128), 256, 0, stream>>>(
      xn_bf, wt_head, out, NTOK, VOCAB, CDIM);
}